// Round 9
// baseline (929.810 us; speedup 1.0000x reference)
//
#include <hip/hip_runtime.h>

// LSTM char-RNN forward: batch=1024, T=512, UNITS=256, NUM_CHARS=128.
// R17 = R16 (831us: R11 structure + polls-first + selective re-poll +
// inp-LDS) + conflict-free exchange->LDS path:
//  1. PAIR-PACKED payloads: one shfl_xor at publish repacks each thread's
//     (u2, u2+32) fp16 halves into consecutive-unit pairs (2j',2j'+1).
//     Every hx word now lands as ONE aligned u32 in the A-frag layout:
//     gather = 3 u32 writes (was 6 u16), own-write = 1 u32 (was 2 u16).
//  2. XOR-SWIZZLED A-frag layout: byte ^= ((k>>3)&3)<<4. Write quarter-
//     waves now hit 16 distinct banks (was 4 banks w/ same-word u16
//     pairs = the 5.03e7 conflict counter, 384 cyc/block/step); read
//     ds_read_b128 stays conflict-free (swizzle only permutes 16B blocks
//     within each quarter-wave's contiguous 256B span).
// Same fp16 values, same hx geometry/volume, same barriers/epilogue ->
// absmax ~6.1e-5. Everything else verbatim R16.
//
// Structure record (R8-R16): 4-way unit split / 8 waves / 3-consumer
// tag-parity agent exchange is the measured optimum; 2-phase multiplex
// (R12), 8-way split (R13), zero-exchange 16-wave (R15) all regressed.

#define TSTEPS 512
#define UNITS  256
#define NCHAR  128
#define G4     1024
#define ZSL    260   // zbuf row stride (256 cols + pad)
#define ISTR   17    // inp_lds row stride (ints)

typedef float    f32x4 __attribute__((ext_vector_type(4)));
typedef _Float16 f16x8 __attribute__((ext_vector_type(8)));
typedef unsigned long long ull;

union FU { uint4 u4; f16x8 h8; _Float16 h[8]; };
union HP { unsigned int u; _Float16 f[2]; };

__device__ __forceinline__ float fast_rcp(float x) {
#if __has_builtin(__builtin_amdgcn_rcpf)
  return __builtin_amdgcn_rcpf(x);
#else
  return 1.0f / x;
#endif
}
__device__ __forceinline__ float sigm(float x)  { return fast_rcp(1.0f + __expf(-x)); }
__device__ __forceinline__ float tanhx(float x) { return 2.0f * fast_rcp(1.0f + __expf(-2.0f * x)) - 1.0f; }

__device__ __forceinline__ ull ld_agent(const ull* p) {
  return __hip_atomic_load(p, __ATOMIC_RELAXED, __HIP_MEMORY_SCOPE_AGENT);
}

// ---- Prep: WhB = Wh fp16 B-fragment stream. idx=(nt*8+kk)*64+l, nt=cc*32+tile.
__global__ void prep_whB(const float* __restrict__ Wh, uint4* __restrict__ WhB) {
  int idx = blockIdx.x * blockDim.x + threadIdx.x;    // 0..32767
  int l    = idx & 63;
  int kk   = (idx >> 6) & 7;
  int tile = (idx >> 9) & 31;
  int cc   = idx >> 14;
  int n    = tile * 16 + (l & 15);
  int gate = n & 3;
  int col  = gate * 256 + cc * 128 + (n >> 2);
  int kb   = kk * 32 + (l >> 4) * 8;
  FU p;
#pragma unroll
  for (int j = 0; j < 8; ++j)
    p.h[j] = (_Float16)Wh[(kb + j) * G4 + col];
  WhB[idx] = p.u4;
}

// ---- Prep: Wxbg[ch][u] = float4(i,f,g,o) = Wx[ch][gate*256+u] + b
__global__ void prep_wx(const float* __restrict__ Wx, const float* __restrict__ bias,
                        float4* __restrict__ Wxbg) {
  int idx = blockIdx.x * blockDim.x + threadIdx.x;    // 0..32767
  int u  = idx & (UNITS - 1);
  int ch = idx >> 8;
  const float* r = Wx + ch * G4;
  float4 o;
  o.x = r[0 * UNITS + u] + bias[0 * UNITS + u];
  o.y = r[1 * UNITS + u] + bias[1 * UNITS + u];
  o.z = r[2 * UNITS + u] + bias[2 * UNITS + u];
  o.w = r[3 * UNITS + u] + bias[3 * UNITS + u];
  Wxbg[idx] = o;
}

// Swizzled A-frag byte address for the u32 word holding units (2j',2j'+1)
// of row r in K-chunk kk (kk = k>>5, d = (k>>3)&3, off = (k&7)>>1 = j'&3).
// Swizzle: byte ^= d<<4 -> quarter-wave writes hit 16 distinct banks.
__device__ __forceinline__ int afrag_pair_addr(int kk, int d, int r, int off) {
  return (((kk * 64 + d * 16 + r) * 16) + off * 4) ^ (d << 4);
}

// ---- Main: 256 blocks x 512 threads. g = bid&63 (group of 16 rows),
// c = bid>>6 (unit quarter: units [c*64, c*64+64)).
__global__ __launch_bounds__(512) void lstm_mfma(
    const int* __restrict__ inp, const uint4* __restrict__ WhB,
    const float4* __restrict__ Wxbg, const float* __restrict__ Wd,
    const float* __restrict__ bd, float* __restrict__ out,
    ull* __restrict__ hx) {
  __shared__ __align__(16) uint4 hfrag[512];     // 8 KB: h_t A-frags (K=256, 16 rows)
  __shared__ float zbuf[16 * ZSL];               // 16.6 KB
  __shared__ __align__(16) int inp_lds[TSTEPS * ISTR];  // 34.8 KB
  __shared__ float lgts[16 * 132];               // 8.4 KB
  __shared__ float rmax[16], rsum[16];

  const int tid  = threadIdx.x;
  const int lane = tid & 63;
  const int wv   = tid >> 6;          // 0..7
  const int bid  = blockIdx.x;
  const int g    = bid & 63;
  const int c    = bid >> 6;          // unit quarter 0..3
  const int r    = tid >> 5;          // 0..15: batch row for gates/publish
  const int u2   = tid & 31;          // unit-within-quarter (first of 2)
  const int jq   = tid & 31;          // gather pair index j' (0..31)

  // partners (the 3 other quarters)
  const int cpa = (c == 0) ? 1 : 0;
  const int cpb = (c <= 1) ? 2 : 1;
  const int cpc = (c <= 2) ? 3 : 2;

  // ---- Weight B-frags: block tiles nt = c*16 + (wv*2, wv*2+1), all 8 kk.
  FU wf0[8], wf1[8];
  const int nt0 = c * 16 + wv * 2, nt1 = nt0 + 1;
#pragma unroll
  for (int kx = 0; kx < 8; ++kx) {
    int i  = kx - 2;
    int kk = (kx < 2) ? (2 * c + kx) : ((i < 2 * c) ? i : i + 2);
    wf0[kx].u4 = WhB[(nt0 * 8 + kk) * 64 + lane];
    wf1[kx].u4 = WhB[(nt1 * 8 + kk) * 64 + lane];
  }
#pragma unroll
  for (int kx = 0; kx < 8; ++kx) {
    asm volatile("" : "+v"(wf0[kx].u4.x), "+v"(wf0[kx].u4.y), "+v"(wf0[kx].u4.z), "+v"(wf0[kx].u4.w));
    asm volatile("" : "+v"(wf1[kx].u4.x), "+v"(wf1[kx].u4.y), "+v"(wf1[kx].u4.z), "+v"(wf1[kx].u4.w));
  }

  // ---- inp staging: inp_lds[t*ISTR + row] (coalesced global reads)
#pragma unroll 1
  for (int i = 0; i < 16; ++i) {
    int e = i * 512 + tid;            // 0..8191
    int row = e >> 9, tt = e & 511;
    inp_lds[tt * ISTR + row] = inp[(g * 16 + row) * TSTEPS + tt];
  }
  if (tid < 512) hfrag[tid] = uint4{0u, 0u, 0u, 0u};   // h_0 = 0 (any layout)
  float cst0 = 0.f, cst1 = 0.f;
  unsigned lastpk = 0;

  // ---- swizzled MFMA read base (per-thread constant): block kk*64+lane,
  // byte ^= ((lane>>4)&3)<<4. Reads stay conflict-free (block permutation
  // within each quarter-wave's contiguous 256B span).
  const int rbase = (lane << 4) ^ (((lane >> 4) & 3) << 4);

  // ---- gather write addrs (3 partner u32 words, thread = (r, jq))
  const int dg  = (jq >> 2) & 3, og = jq & 3, kg = jq >> 4;
  const int gwa = afrag_pair_addr(2 * cpa + kg, dg, r, og);
  const int gwb = afrag_pair_addr(2 * cpb + kg, dg, r, og);
  const int gwc = afrag_pair_addr(2 * cpc + kg, dg, r, og);
  // ---- own publish word: even u2 -> pair (u2,u2+1) at j'=u2>>1;
  //      odd u2 -> pair (u2+31,u2+32+1)... = (2j',2j'+1) with j'=(u2>>1)+16.
  const int jown = (u2 >> 1) + ((u2 & 1) << 4);
  const int aownw = afrag_pair_addr(2 * c + (jown >> 4), (jown >> 2) & 3, r, jown & 3);

  __syncthreads();

  for (int t = 0; t < TSTEPS; ++t) {
    // ---- polls FIRST: 3 independent agent loads, RT starts immediately
    ull v0 = 0, v1 = 0, v2 = 0;
    const ull* pb = hx + (((t & 1) * 64 + g) << 11) + tid;
    if (t > 0) {
      v0 = ld_agent(pb + (cpa << 9));
      v1 = ld_agent(pb + (cpb << 9));
      v2 = ld_agent(pb + (cpc << 9));
    }

    int    ch  = inp_lds[t * ISTR + r];
    float4 xb0 = Wxbg[ch * 256 + c * 64 + u2];
    float4 xb1 = Wxbg[ch * 256 + c * 64 + u2 + 32];

    // ---- own-chunk K MFMA (kk = 2c, 2c+1); t=0: hfrag = 0
    f32x4 acc0 = {0.f, 0.f, 0.f, 0.f}, acc1 = {0.f, 0.f, 0.f, 0.f};
#pragma unroll
    for (int kx = 0; kx < 2; ++kx) {
      int kk = 2 * c + kx;
      FU a; a.u4 = *(const uint4*)((const char*)hfrag + (kk << 10) + rbase);
      acc0 = __builtin_amdgcn_mfma_f32_16x16x32_f16(a.h8, wf0[kx].h8, acc0, 0, 0, 0);
      acc1 = __builtin_amdgcn_mfma_f32_16x16x32_f16(a.h8, wf1[kx].h8, acc1, 0, 0, 0);
    }

    if (t > 0) {
      // ---- fused detect+gather: all 3 tags must equal t; selective re-poll
      const unsigned tu = (unsigned)t;
      long guard = 0;
      while (((((unsigned)(v0 >> 32)) ^ tu) |
              (((unsigned)(v1 >> 32)) ^ tu) |
              (((unsigned)(v2 >> 32)) ^ tu)) != 0u) {
        if (++guard >= (1L << 14)) break;
        if ((unsigned)(v0 >> 32) != tu) v0 = ld_agent(pb + (cpa << 9));
        if ((unsigned)(v1 >> 32) != tu) v1 = ld_agent(pb + (cpb << 9));
        if ((unsigned)(v2 >> 32) != tu) v2 = ld_agent(pb + (cpc << 9));
      }
      // pair-packed payloads -> single aligned u32 per partner word
      *(unsigned*)((char*)hfrag + gwa) = (unsigned)v0;
      *(unsigned*)((char*)hfrag + gwb) = (unsigned)v1;
      *(unsigned*)((char*)hfrag + gwc) = (unsigned)v2;
    }
    __syncthreads();   // hfrag complete

    // ---- remaining 6 K-chunks
#pragma unroll
    for (int kx = 2; kx < 8; ++kx) {
      int i  = kx - 2;
      int kk = (i < 2 * c) ? i : i + 2;
      FU a; a.u4 = *(const uint4*)((const char*)hfrag + (kk << 10) + rbase);
      acc0 = __builtin_amdgcn_mfma_f32_16x16x32_f16(a.h8, wf0[kx].h8, acc0, 0, 0, 0);
      acc1 = __builtin_amdgcn_mfma_f32_16x16x32_f16(a.h8, wf1[kx].h8, acc1, 0, 0, 0);
    }
    {
      const int cq = lane >> 4, cn = lane & 15;   // C: row=(lane>>4)*4+reg
#pragma unroll
      for (int reg = 0; reg < 4; ++reg) {
        zbuf[(cq * 4 + reg) * ZSL + (wv * 2)     * 16 + cn] = acc0[reg];
        zbuf[(cq * 4 + reg) * ZSL + (wv * 2 + 1) * 16 + cn] = acc1[reg];
      }
    }
    __syncthreads();   // zbuf ready

    // ---- gates: thread = (row r, units u0 = c*64+u2, u1 = u0+32)
    {
      float4 z0 = *(const float4*)&zbuf[r * ZSL + u2 * 4];
      float4 z1 = *(const float4*)&zbuf[r * ZSL + u2 * 4 + 128];
      float i0 = sigm(z0.x + xb0.x), f0 = sigm(z0.y + xb0.y);
      float g0 = tanhx(z0.z + xb0.z), o0 = sigm(z0.w + xb0.w);
      cst0 = f0 * cst0 + i0 * g0;
      float h0 = o0 * tanhx(cst0);
      float i1 = sigm(z1.x + xb1.x), f1 = sigm(z1.y + xb1.y);
      float g1 = tanhx(z1.z + xb1.z), o1 = sigm(z1.w + xb1.w);
      cst1 = f1 * cst1 + i1 * g1;
      float h1 = o1 * tanhx(cst1);

      HP p; p.f[0] = (_Float16)h0; p.f[1] = (_Float16)h1;
      lastpk = p.u;
      // pair-pack with the adjacent thread: even -> (u2,u2+1) lows,
      // odd -> (u2+31+1, u2+32+1) highs. One shfl_xor serves both.
      unsigned other = (unsigned)__shfl_xor((int)p.u, 1, 64);
      unsigned val32 = (u2 & 1) ? ((other >> 16)    | (p.u & 0xffff0000u))
                                : ((p.u & 0xffffu)  | (other << 16));
      // own pair straight into the (swizzled) A-frag slot
      *(unsigned*)((char*)hfrag + aownw) = val32;
      // publish tagged payload (fire-and-forget; self-validating)
      ull val = ((ull)(unsigned)(t + 1) << 32) | (ull)val32;
      __hip_atomic_store(hx + ((((t + 1) & 1) * 64 + g) << 11) + (c << 9) + r * 32 + jown,
                         val, __ATOMIC_RELAXED, __HIP_MEMORY_SCOPE_AGENT);
    }
    __syncthreads();   // hfrag own-writes + zbuf handoff for next iteration
  }

  if (c != 0) return;

  // ---- Epilogue (c==0): h_T -> fp32 (16 rows x 256), Wd, softmax.
  // Own quarter from lastpk; 3 partner quarters polled (tag==TSTEPS, par=0).
  {
    HP p; p.u = lastpk;
    zbuf[r * ZSL + u2]      = (float)p.f[0];
    zbuf[r * ZSL + u2 + 32] = (float)p.f[1];

    const ull* pb = hx + ((0 * 64 + g) << 11) + tid;  // parity 0
    const unsigned tu = (unsigned)TSTEPS;
    ull v0 = ld_agent(pb + (1 << 9));
    ull v1 = ld_agent(pb + (2 << 9));
    ull v2 = ld_agent(pb + (3 << 9));
    long guard = 0;
    while (((((unsigned)(v0 >> 32)) ^ tu) |
            (((unsigned)(v1 >> 32)) ^ tu) |
            (((unsigned)(v2 >> 32)) ^ tu)) != 0u) {
      if (++guard >= (1L << 14)) break;
      if ((unsigned)(v0 >> 32) != tu) v0 = ld_agent(pb + (1 << 9));
      if ((unsigned)(v1 >> 32) != tu) v1 = ld_agent(pb + (2 << 9));
      if ((unsigned)(v2 >> 32) != tu) v2 = ld_agent(pb + (3 << 9));
    }
    // pair-packed: word (cp, r, jq) = units (2jq, 2jq+1) of quarter cp
    HP q;
    q.u = (unsigned)v0;
    zbuf[r * ZSL + 1 * 64 + 2 * jq]     = (float)q.f[0];
    zbuf[r * ZSL + 1 * 64 + 2 * jq + 1] = (float)q.f[1];
    q.u = (unsigned)v1;
    zbuf[r * ZSL + 2 * 64 + 2 * jq]     = (float)q.f[0];
    zbuf[r * ZSL + 2 * 64 + 2 * jq + 1] = (float)q.f[1];
    q.u = (unsigned)v2;
    zbuf[r * ZSL + 3 * 64 + 2 * jq]     = (float)q.f[0];
    zbuf[r * ZSL + 3 * 64 + 2 * jq + 1] = (float)q.f[1];
  }
  __syncthreads();
  {
    const int j  = tid & 127;
    const int rb = tid >> 7;            // 0..3 -> rows 4rb..4rb+3
    const int r0 = rb * 4;
    float l0 = bd[j], l1 = bd[j], l2 = bd[j], l3 = bd[j];
    for (int k = 0; k < 256; ++k) {
      float w = Wd[k * NCHAR + j];
      l0 += zbuf[(r0 + 0) * ZSL + k] * w;
      l1 += zbuf[(r0 + 1) * ZSL + k] * w;
      l2 += zbuf[(r0 + 2) * ZSL + k] * w;
      l3 += zbuf[(r0 + 3) * ZSL + k] * w;
    }
    lgts[(r0 + 0) * 132 + j] = l0;
    lgts[(r0 + 1) * 132 + j] = l1;
    lgts[(r0 + 2) * 132 + j] = l2;
    lgts[(r0 + 3) * 132 + j] = l3;
  }
  __syncthreads();
  if (tid < 16) {
    const int rr = tid;
    float m = -1e30f;
    for (int j = 0; j < NCHAR; ++j) m = fmaxf(m, lgts[rr * 132 + j]);
    float s = 0.f;
    for (int j = 0; j < NCHAR; ++j) s += __expf(lgts[rr * 132 + j] - m);
    rmax[rr] = m;
    rsum[rr] = fast_rcp(s);
  }
  __syncthreads();
  {
    const int j  = tid & 127;
    const int rb = tid >> 7;
#pragma unroll
    for (int ii = 0; ii < 4; ++ii) {
      int rr = rb * 4 + ii;
      out[(g * 16 + rr) * NCHAR + j] = __expf(lgts[rr * 132 + j] - rmax[rr]) * rsum[rr];
    }
  }
}

extern "C" void kernel_launch(void* const* d_in, const int* in_sizes, int n_in,
                              void* d_out, int out_size, void* d_ws, size_t ws_size,
                              hipStream_t stream) {
  const int*   inp = (const int*)d_in[0];
  const float* Wx  = (const float*)d_in[1];
  const float* Wh  = (const float*)d_in[2];
  const float* bia = (const float*)d_in[3];
  const float* Wd  = (const float*)d_in[4];
  const float* bd  = (const float*)d_in[5];

  uint4*  WhB  = (uint4*)d_ws;                          // 512 KB
  float4* Wxbg = (float4*)((char*)d_ws + (512 << 10));  // 512 KB
  ull*    hx   = (ull*)((char*)d_ws + (1 << 20));       // 2 MB

  prep_whB<<<128, 256, 0, stream>>>(Wh, WhB);
  prep_wx<<<128, 256, 0, stream>>>(Wx, bia, Wxbg);
  lstm_mfma<<<256, 512, 0, stream>>>(inp, WhB, Wxbg, Wd, bd, (float*)d_out, hx);
}

// Round 10
// 772.328 us; speedup vs baseline: 1.2039x; 1.2039x over previous
//
#include <hip/hip_runtime.h>

// LSTM char-RNN forward: batch=1024, T=512, UNITS=256, NUM_CHARS=128.
// R18 = R16 (831us, best) + split sibling-MFMA accumulator chains.
//
// R17 post-mortem: killing the LDS bank conflicts (5.03e7 -> 8.4e6,
// predicted) REGRESSED timing (+95us) because the fix put a shfl_xor on
// the serial recurrence chain (gather -> MFMA -> zbuf -> gates ->
// publish), which is paid 512x and propagates to consumer blocks. The
// conflicts were slack-absorbed all along. Lesson: only the chain counts.
// R18 reverts to R16 byte-for-byte and shortens the chain's MFMA
// segment: the 6 post-gather MFMAs per tile-acc were one dependent chain
// (~120cyc); splitting into two independent chains (kx 2..4 -> acc,
// kx 5..7 -> accb, one add before zbuf) halves that latency. fp32
// regroup is absmax-safe: absmax has been bit-identical (6.103516e-05 =
// 2^-14, the fp16 quantum) across all chunk-order variants R8-R17 --
// it is fp16-rounding-dominated, not fp32-order-dominated.

#define TSTEPS 512
#define UNITS  256
#define NCHAR  128
#define G4     1024
#define ZSL    260   // zbuf row stride (256 cols + pad)
#define ISTR   17    // inp_lds row stride (ints)

typedef float    f32x4 __attribute__((ext_vector_type(4)));
typedef _Float16 f16x8 __attribute__((ext_vector_type(8)));
typedef unsigned long long ull;

union FU { uint4 u4; f16x8 h8; _Float16 h[8]; };
union HP { unsigned int u; _Float16 f[2]; };

__device__ __forceinline__ float fast_rcp(float x) {
#if __has_builtin(__builtin_amdgcn_rcpf)
  return __builtin_amdgcn_rcpf(x);
#else
  return 1.0f / x;
#endif
}
__device__ __forceinline__ float sigm(float x)  { return fast_rcp(1.0f + __expf(-x)); }
__device__ __forceinline__ float tanhx(float x) { return 2.0f * fast_rcp(1.0f + __expf(-2.0f * x)) - 1.0f; }

__device__ __forceinline__ ull ld_agent(const ull* p) {
  return __hip_atomic_load(p, __ATOMIC_RELAXED, __HIP_MEMORY_SCOPE_AGENT);
}

// ---- Prep: WhB = Wh fp16 B-fragment stream. idx=(nt*8+kk)*64+l, nt=cc*32+tile.
__global__ void prep_whB(const float* __restrict__ Wh, uint4* __restrict__ WhB) {
  int idx = blockIdx.x * blockDim.x + threadIdx.x;    // 0..32767
  int l    = idx & 63;
  int kk   = (idx >> 6) & 7;
  int tile = (idx >> 9) & 31;
  int cc   = idx >> 14;
  int n    = tile * 16 + (l & 15);
  int gate = n & 3;
  int col  = gate * 256 + cc * 128 + (n >> 2);
  int kb   = kk * 32 + (l >> 4) * 8;
  FU p;
#pragma unroll
  for (int j = 0; j < 8; ++j)
    p.h[j] = (_Float16)Wh[(kb + j) * G4 + col];
  WhB[idx] = p.u4;
}

// ---- Prep: Wxbg[ch][u] = float4(i,f,g,o) = Wx[ch][gate*256+u] + b
__global__ void prep_wx(const float* __restrict__ Wx, const float* __restrict__ bias,
                        float4* __restrict__ Wxbg) {
  int idx = blockIdx.x * blockDim.x + threadIdx.x;    // 0..32767
  int u  = idx & (UNITS - 1);
  int ch = idx >> 8;
  const float* r = Wx + ch * G4;
  float4 o;
  o.x = r[0 * UNITS + u] + bias[0 * UNITS + u];
  o.y = r[1 * UNITS + u] + bias[1 * UNITS + u];
  o.z = r[2 * UNITS + u] + bias[2 * UNITS + u];
  o.w = r[3 * UNITS + u] + bias[3 * UNITS + u];
  Wxbg[idx] = o;
}

// A-frag LDS byte address for h element (row m, k). Proven layout (R8/R11).
__device__ __forceinline__ int afrag_addr(int k, int m) {
  return ((k >> 5) << 10) + (((((k >> 3) & 3) << 4) + m) << 4) + ((k & 7) << 1);
}

// ---- Main: 256 blocks x 512 threads. g = bid&63 (group of 16 rows),
// c = bid>>6 (unit quarter: units [c*64, c*64+64)).
__global__ __launch_bounds__(512) void lstm_mfma(
    const int* __restrict__ inp, const uint4* __restrict__ WhB,
    const float4* __restrict__ Wxbg, const float* __restrict__ Wd,
    const float* __restrict__ bd, float* __restrict__ out,
    ull* __restrict__ hx) {
  __shared__ __align__(16) uint4 hfrag[512];     // 8 KB: h_t A-frags (K=256, 16 rows)
  __shared__ float zbuf[16 * ZSL];               // 16.6 KB
  __shared__ __align__(16) int inp_lds[TSTEPS * ISTR];  // 34.8 KB
  __shared__ float lgts[16 * 132];               // 8.4 KB
  __shared__ float rmax[16], rsum[16];

  const int tid  = threadIdx.x;
  const int lane = tid & 63;
  const int wv   = tid >> 6;          // 0..7
  const int bid  = blockIdx.x;
  const int g    = bid & 63;
  const int c    = bid >> 6;          // unit quarter 0..3
  const int r    = tid >> 5;          // 0..15: batch row for gates/publish
  const int u2   = tid & 31;          // unit-within-quarter (first of 2)

  // partners (the 3 other quarters)
  const int cpa = (c == 0) ? 1 : 0;
  const int cpb = (c <= 1) ? 2 : 1;
  const int cpc = (c <= 2) ? 3 : 2;

  // ---- Weight B-frags: block tiles nt = c*16 + (wv*2, wv*2+1), all 8 kk.
  // kk slot order: slots 0,1 = own K-chunk (kk = 2c, 2c+1); slots 2..7 =
  // the remaining kk ascending. (A-side read uses the same mapping.)
  FU wf0[8], wf1[8];
  const int nt0 = c * 16 + wv * 2, nt1 = nt0 + 1;
#pragma unroll
  for (int kx = 0; kx < 8; ++kx) {
    int i  = kx - 2;
    int kk = (kx < 2) ? (2 * c + kx) : ((i < 2 * c) ? i : i + 2);
    wf0[kx].u4 = WhB[(nt0 * 8 + kk) * 64 + lane];
    wf1[kx].u4 = WhB[(nt1 * 8 + kk) * 64 + lane];
  }
#pragma unroll
  for (int kx = 0; kx < 8; ++kx) {
    asm volatile("" : "+v"(wf0[kx].u4.x), "+v"(wf0[kx].u4.y), "+v"(wf0[kx].u4.z), "+v"(wf0[kx].u4.w));
    asm volatile("" : "+v"(wf1[kx].u4.x), "+v"(wf1[kx].u4.y), "+v"(wf1[kx].u4.z), "+v"(wf1[kx].u4.w));
  }

  // ---- inp staging: inp_lds[t*ISTR + row] (coalesced global reads)
#pragma unroll 1
  for (int i = 0; i < 16; ++i) {
    int e = i * 512 + tid;            // 0..8191
    int row = e >> 9, tt = e & 511;
    inp_lds[tt * ISTR + row] = inp[(g * 16 + row) * TSTEPS + tt];
  }
  if (tid < 512) hfrag[tid] = uint4{0u, 0u, 0u, 0u};   // h_0 = 0
  float cst0 = 0.f, cst1 = 0.f;
  unsigned lastpk = 0;

  // A-frag byte addresses: own 2 units, 3 partners x 2 units.
  const int oa0 = afrag_addr(c   * 64 + u2,      r);
  const int oa1 = afrag_addr(c   * 64 + u2 + 32, r);
  const int ga0 = afrag_addr(cpa * 64 + u2,      r);
  const int ga1 = afrag_addr(cpa * 64 + u2 + 32, r);
  const int gb0 = afrag_addr(cpb * 64 + u2,      r);
  const int gb1 = afrag_addr(cpb * 64 + u2 + 32, r);
  const int gc0 = afrag_addr(cpc * 64 + u2,      r);
  const int gc1 = afrag_addr(cpc * 64 + u2 + 32, r);
  __syncthreads();

  for (int t = 0; t < TSTEPS; ++t) {
    // ---- polls FIRST: 3 independent agent loads, RT starts immediately
    ull v0 = 0, v1 = 0, v2 = 0;
    const ull* pb = hx + (((t & 1) * 64 + g) << 11) + tid;
    if (t > 0) {
      v0 = ld_agent(pb + (cpa << 9));
      v1 = ld_agent(pb + (cpb << 9));
      v2 = ld_agent(pb + (cpc << 9));
    }

    int    ch  = inp_lds[t * ISTR + r];
    float4 xb0 = Wxbg[ch * 256 + c * 64 + u2];
    float4 xb1 = Wxbg[ch * 256 + c * 64 + u2 + 32];

    // ---- own-chunk K MFMA (kk = 2c, 2c+1); t=0: hfrag = 0
    f32x4 acc0 = {0.f, 0.f, 0.f, 0.f}, acc1 = {0.f, 0.f, 0.f, 0.f};
#pragma unroll
    for (int kx = 0; kx < 2; ++kx) {
      int kk = 2 * c + kx;
      FU a; a.u4 = hfrag[kk * 64 + lane];
      acc0 = __builtin_amdgcn_mfma_f32_16x16x32_f16(a.h8, wf0[kx].h8, acc0, 0, 0, 0);
      acc1 = __builtin_amdgcn_mfma_f32_16x16x32_f16(a.h8, wf1[kx].h8, acc1, 0, 0, 0);
    }

    if (t > 0) {
      // ---- fused detect+gather: all 3 tags must equal t; SELECTIVE
      // re-poll (only stale words) -> shorter loop period, less traffic.
      const unsigned tu = (unsigned)t;
      long guard = 0;
      while (((((unsigned)(v0 >> 32)) ^ tu) |
              (((unsigned)(v1 >> 32)) ^ tu) |
              (((unsigned)(v2 >> 32)) ^ tu)) != 0u) {
        if (++guard >= (1L << 14)) break;
        if ((unsigned)(v0 >> 32) != tu) v0 = ld_agent(pb + (cpa << 9));
        if ((unsigned)(v1 >> 32) != tu) v1 = ld_agent(pb + (cpb << 9));
        if ((unsigned)(v2 >> 32) != tu) v2 = ld_agent(pb + (cpc << 9));
      }
      *(unsigned short*)((char*)hfrag + ga0) = (unsigned short)v0;
      *(unsigned short*)((char*)hfrag + ga1) = (unsigned short)(v0 >> 16);
      *(unsigned short*)((char*)hfrag + gb0) = (unsigned short)v1;
      *(unsigned short*)((char*)hfrag + gb1) = (unsigned short)(v1 >> 16);
      *(unsigned short*)((char*)hfrag + gc0) = (unsigned short)v2;
      *(unsigned short*)((char*)hfrag + gc1) = (unsigned short)(v2 >> 16);
    }
    __syncthreads();   // hfrag complete

    // ---- remaining 6 K-chunks: TWO independent dependency chains per
    // tile (kx 2..4 continue acc, kx 5..7 into accb) -> post-gather MFMA
    // latency chain depth 6 -> 3. One add each before zbuf.
    f32x4 acc0b = {0.f, 0.f, 0.f, 0.f}, acc1b = {0.f, 0.f, 0.f, 0.f};
#pragma unroll
    for (int kx = 2; kx < 5; ++kx) {
      int i  = kx - 2;
      int kk = (i < 2 * c) ? i : i + 2;
      FU a; a.u4 = hfrag[kk * 64 + lane];
      acc0 = __builtin_amdgcn_mfma_f32_16x16x32_f16(a.h8, wf0[kx].h8, acc0, 0, 0, 0);
      acc1 = __builtin_amdgcn_mfma_f32_16x16x32_f16(a.h8, wf1[kx].h8, acc1, 0, 0, 0);
    }
#pragma unroll
    for (int kx = 5; kx < 8; ++kx) {
      int i  = kx - 2;
      int kk = (i < 2 * c) ? i : i + 2;
      FU a; a.u4 = hfrag[kk * 64 + lane];
      acc0b = __builtin_amdgcn_mfma_f32_16x16x32_f16(a.h8, wf0[kx].h8, acc0b, 0, 0, 0);
      acc1b = __builtin_amdgcn_mfma_f32_16x16x32_f16(a.h8, wf1[kx].h8, acc1b, 0, 0, 0);
    }
    {
      const int cq = lane >> 4, cn = lane & 15;   // C: row=(lane>>4)*4+reg
#pragma unroll
      for (int reg = 0; reg < 4; ++reg) {
        zbuf[(cq * 4 + reg) * ZSL + (wv * 2)     * 16 + cn] = acc0[reg] + acc0b[reg];
        zbuf[(cq * 4 + reg) * ZSL + (wv * 2 + 1) * 16 + cn] = acc1[reg] + acc1b[reg];
      }
    }
    __syncthreads();   // zbuf ready

    // ---- gates: thread = (row r, units u0 = c*64+u2, u1 = u0+32)
    {
      float4 z0 = *(const float4*)&zbuf[r * ZSL + u2 * 4];
      float4 z1 = *(const float4*)&zbuf[r * ZSL + u2 * 4 + 128];
      float i0 = sigm(z0.x + xb0.x), f0 = sigm(z0.y + xb0.y);
      float g0 = tanhx(z0.z + xb0.z), o0 = sigm(z0.w + xb0.w);
      cst0 = f0 * cst0 + i0 * g0;
      float h0 = o0 * tanhx(cst0);
      float i1 = sigm(z1.x + xb1.x), f1 = sigm(z1.y + xb1.y);
      float g1 = tanhx(z1.z + xb1.z), o1 = sigm(z1.w + xb1.w);
      cst1 = f1 * cst1 + i1 * g1;
      float h1 = o1 * tanhx(cst1);

      HP p; p.f[0] = (_Float16)h0; p.f[1] = (_Float16)h1;
      lastpk = p.u;
      // own units straight to own A-frag slots
      *(unsigned short*)((char*)hfrag + oa0) = (unsigned short)p.u;
      *(unsigned short*)((char*)hfrag + oa1) = (unsigned short)(p.u >> 16);
      // publish tagged payload (fire-and-forget; self-validating)
      ull val = ((ull)(unsigned)(t + 1) << 32) | (ull)p.u;
      __hip_atomic_store(hx + ((((t + 1) & 1) * 64 + g) << 11) + (c << 9) + tid, val,
                         __ATOMIC_RELAXED, __HIP_MEMORY_SCOPE_AGENT);
    }
    __syncthreads();   // hfrag own-writes + zbuf handoff for next iteration
  }

  if (c != 0) return;

  // ---- Epilogue (c==0): h_T -> fp32 (16 rows x 256), Wd, softmax.
  // Own quarter from lastpk; 3 partner quarters polled (tag==TSTEPS, par=0).
  {
    HP p; p.u = lastpk;
    zbuf[r * ZSL + u2]      = (float)p.f[0];
    zbuf[r * ZSL + u2 + 32] = (float)p.f[1];

    const ull* pb = hx + ((0 * 64 + g) << 11) + tid;  // parity 0
    const unsigned tu = (unsigned)TSTEPS;
    ull v0 = ld_agent(pb + (1 << 9));
    ull v1 = ld_agent(pb + (2 << 9));
    ull v2 = ld_agent(pb + (3 << 9));
    long guard = 0;
    while (((((unsigned)(v0 >> 32)) ^ tu) |
            (((unsigned)(v1 >> 32)) ^ tu) |
            (((unsigned)(v2 >> 32)) ^ tu)) != 0u) {
      if (++guard >= (1L << 14)) break;
      if ((unsigned)(v0 >> 32) != tu) v0 = ld_agent(pb + (1 << 9));
      if ((unsigned)(v1 >> 32) != tu) v1 = ld_agent(pb + (2 << 9));
      if ((unsigned)(v2 >> 32) != tu) v2 = ld_agent(pb + (3 << 9));
    }
    HP q;
    q.u = (unsigned)v0;
    zbuf[r * ZSL +  64 + u2] = (float)q.f[0];
    zbuf[r * ZSL +  96 + u2] = (float)q.f[1];
    q.u = (unsigned)v1;
    zbuf[r * ZSL + 128 + u2] = (float)q.f[0];
    zbuf[r * ZSL + 160 + u2] = (float)q.f[1];
    q.u = (unsigned)v2;
    zbuf[r * ZSL + 192 + u2] = (float)q.f[0];
    zbuf[r * ZSL + 224 + u2] = (float)q.f[1];
  }
  __syncthreads();
  {
    const int j  = tid & 127;
    const int rb = tid >> 7;            // 0..3 -> rows 4rb..4rb+3
    const int r0 = rb * 4;
    float l0 = bd[j], l1 = bd[j], l2 = bd[j], l3 = bd[j];
    for (int k = 0; k < 256; ++k) {
      float w = Wd[k * NCHAR + j];
      l0 += zbuf[(r0 + 0) * ZSL + k] * w;
      l1 += zbuf[(r0 + 1) * ZSL + k] * w;
      l2 += zbuf[(r0 + 2) * ZSL + k] * w;
      l3 += zbuf[(r0 + 3) * ZSL + k] * w;
    }
    lgts[(r0 + 0) * 132 + j] = l0;
    lgts[(r0 + 1) * 132 + j] = l1;
    lgts[(r0 + 2) * 132 + j] = l2;
    lgts[(r0 + 3) * 132 + j] = l3;
  }
  __syncthreads();
  if (tid < 16) {
    const int rr = tid;
    float m = -1e30f;
    for (int j = 0; j < NCHAR; ++j) m = fmaxf(m, lgts[rr * 132 + j]);
    float s = 0.f;
    for (int j = 0; j < NCHAR; ++j) s += __expf(lgts[rr * 132 + j] - m);
    rmax[rr] = m;
    rsum[rr] = fast_rcp(s);
  }
  __syncthreads();
  {
    const int j  = tid & 127;
    const int rb = tid >> 7;
#pragma unroll
    for (int ii = 0; ii < 4; ++ii) {
      int rr = rb * 4 + ii;
      out[(g * 16 + rr) * NCHAR + j] = __expf(lgts[rr * 132 + j] - rmax[rr]) * rsum[rr];
    }
  }
}

extern "C" void kernel_launch(void* const* d_in, const int* in_sizes, int n_in,
                              void* d_out, int out_size, void* d_ws, size_t ws_size,
                              hipStream_t stream) {
  const int*   inp = (const int*)d_in[0];
  const float* Wx  = (const float*)d_in[1];
  const float* Wh  = (const float*)d_in[2];
  const float* bia = (const float*)d_in[3];
  const float* Wd  = (const float*)d_in[4];
  const float* bd  = (const float*)d_in[5];

  uint4*  WhB  = (uint4*)d_ws;                          // 512 KB
  float4* Wxbg = (float4*)((char*)d_ws + (512 << 10));  // 512 KB
  ull*    hx   = (ull*)((char*)d_ws + (1 << 20));       // 2 MB

  prep_whB<<<128, 256, 0, stream>>>(Wh, WhB);
  prep_wx<<<128, 256, 0, stream>>>(Wx, bia, Wxbg);
  lstm_mfma<<<256, 512, 0, stream>>>(inp, WhB, Wxbg, Wd, bd, (float*)d_out, hx);
}